// Round 2
// baseline (33.621 us; speedup 1.0000x reference)
//
#include <hip/hip_runtime.h>

#define EPS    1e-5f
#define NSLOPE 0.01f
#define B 4
#define N 256
#define F 128

// workspace float layout
#define WS_WE0 0                 // we0[g]*s1[g]            (128)
#define WS_WE1 128               // we1[g]*s1[g]            (128)
#define WS_PF0 256               // weff[0][g]              (128)
#define WS_PF1 384               // weff[1][g]              (128)
#define WS_C   512               // c[0..1]
#define WS_S1  520               // s1[g]
#define WS_T1  648               // t1[g]
#define WS_WLT 2048              // wlT[f][g] = w1[g][2+f]*s1[g]    (128*128)
#define WS_WRT (WS_WLT + F*F)    // wrT[f][g] = w1[g][130+f]*s1[g]  (128*128)
#define WS_HL  (WS_WRT + F*F)    // hl''[row,g] = hl*s1+t1  (B*N*F)
#define WS_HR  (WS_HL + B*N*F)   // hr'[row,g]  = hr*s1     (B*N*F)

// ---------------------------------------------------------------- prepA
// block 0: fold affine head/tail into WE/PF/C + write s1/t1.
// blocks 1..128: transposed, s1-scaled copy of w1 -> wlT/wrT (coalesced writes).
__global__ __launch_bounds__(128) void prepA(
    const float* __restrict__ w1,
    const float* __restrict__ g1, const float* __restrict__ b1,
    const float* __restrict__ m1, const float* __restrict__ v1,
    const float* __restrict__ w2,
    const float* __restrict__ g2, const float* __restrict__ b2,
    const float* __restrict__ m2, const float* __restrict__ v2,
    const float* __restrict__ pw, const float* __restrict__ pb,
    float* __restrict__ ws) {
  int g = threadIdx.x;
  if (blockIdx.x != 0) {
    int f = blockIdx.x - 1;
    float s1v = g1[g] / sqrtf(v1[g] + EPS);
    ws[WS_WLT + f * F + g] = w1[g * 258 + 2 + f] * s1v;    // gather read, coalesced write
    ws[WS_WRT + f * F + g] = w1[g * 258 + 130 + f] * s1v;
    return;
  }
  __shared__ float s2s[F], t2s[F];
  float s1v = g1[g] / sqrtf(v1[g] + EPS);
  ws[WS_S1 + g] = s1v;
  ws[WS_T1 + g] = b1[g] - m1[g] * s1v;
  ws[WS_WE0 + g] = w1[g * 258 + 0] * s1v;
  ws[WS_WE1 + g] = w1[g * 258 + 1] * s1v;
  float s2v = g2[g] / sqrtf(v2[g] + EPS);
  s2s[g] = s2v;
  t2s[g] = b2[g] - m2[g] * s2v;
  __syncthreads();
  float a0 = 0.f, a1 = 0.f;
  for (int f = 0; f < F; ++f) {
    float wv = w2[f * F + g];                 // coalesced (g fastest)
    a0 = fmaf(pw[f]     * s2s[f], wv, a0);
    a1 = fmaf(pw[F + f] * s2s[f], wv, a1);
  }
  ws[WS_PF0 + g] = a0;
  ws[WS_PF1 + g] = a1;
  if (g < 2) {
    float c = pb[g];
    for (int f = 0; f < F; ++f) c += pw[g * F + f] * t2s[f];
    ws[WS_C + g] = c;
  }
}

// ---------------------------------------------------------------- prepB
// hl''[row,g], hr'[row,g] via transposed weights (coalesced lane-g reads).
// 256 blocks x 128 threads, 4 rows per block.
__global__ __launch_bounds__(128) void prepB(
    const float* __restrict__ node, const float* __restrict__ ws_c,
    float* __restrict__ ws) {
  __shared__ float ns[4][F];
  int t = threadIdx.x;
  int r0 = blockIdx.x * 4;
  {
    int r = t >> 5, c = (t & 31) * 4;
    *reinterpret_cast<float4*>(&ns[r][c]) =
        *reinterpret_cast<const float4*>(node + (size_t)(r0 + r) * F + c);
  }
  __syncthreads();
  int g = t;
  const float* wlT = ws_c + WS_WLT;
  const float* wrT = ws_c + WS_WRT;
  float al[4] = {0.f, 0.f, 0.f, 0.f};
  float ar[4] = {0.f, 0.f, 0.f, 0.f};
  #pragma unroll 4
  for (int f = 0; f < F; ++f) {
    float wl = wlT[f * F + g];     // coalesced, L2-resident
    float wr = wrT[f * F + g];
    #pragma unroll
    for (int r = 0; r < 4; ++r) {
      float nv = ns[r][f];         // LDS broadcast; unroll-4 merges to b128
      al[r] = fmaf(nv, wl, al[r]);
      ar[r] = fmaf(nv, wr, ar[r]);
    }
  }
  float t1v = ws_c[WS_T1 + g];
  float* hl = ws + WS_HL;
  float* hr = ws + WS_HR;
  #pragma unroll
  for (int r = 0; r < 4; ++r) {
    hl[(size_t)(r0 + r) * F + g] = al[r] + t1v;   // s1 folded into wlT
    hr[(size_t)(r0 + r) * F + g] = ar[r];
  }
}

// ---------------------------------------------------------------- main
// grid (8,8,B), block 256: 32x32 (i,j) tile, 2x2 outputs per thread.
// W/P staged in LDS (broadcast ds_read), hl/hr tiles in LDS.
__global__ __launch_bounds__(256) void fused_main(
    const float* __restrict__ edge,
    const float* __restrict__ ws, float* __restrict__ out) {
  __shared__ float hls[32][132];
  __shared__ float hrs[32][132];
  __shared__ float wps[4][F];      // rows: WE0, WE1, PF0, PF1
  int b = blockIdx.z, i0 = blockIdx.y * 32, j0 = blockIdx.x * 32;
  int t = threadIdx.x;
  const float* hl = ws + WS_HL;
  const float* hr = ws + WS_HR;
  {
    int r = t >> 3, cq = (t & 7) * 16;
    const float* sl = hl + (size_t)(b * N + i0 + r) * F + cq;
    const float* sr = hr + (size_t)(b * N + j0 + r) * F + cq;
    #pragma unroll
    for (int k = 0; k < 4; ++k) {
      *reinterpret_cast<float4*>(&hls[r][cq + 4 * k]) =
          *reinterpret_cast<const float4*>(sl + 4 * k);
      *reinterpret_cast<float4*>(&hrs[r][cq + 4 * k]) =
          *reinterpret_cast<const float4*>(sr + 4 * k);
    }
    reinterpret_cast<float2*>(&wps[0][0])[t] =
        reinterpret_cast<const float2*>(ws)[t];   // WE0|WE1|PF0|PF1 = ws[0..511]
  }
  __syncthreads();
  int ti = t >> 4, tj = t & 15;
  int i1 = i0 + ti, i2 = i1 + 16, j1 = j0 + tj, j2 = j1 + 16;
  const float2* e00p = reinterpret_cast<const float2*>(edge + ((size_t)(b * N + i1) * N + j1) * 2);
  const float2* e01p = reinterpret_cast<const float2*>(edge + ((size_t)(b * N + i1) * N + j2) * 2);
  const float2* e10p = reinterpret_cast<const float2*>(edge + ((size_t)(b * N + i2) * N + j1) * 2);
  const float2* e11p = reinterpret_cast<const float2*>(edge + ((size_t)(b * N + i2) * N + j2) * 2);
  float2 e00 = *e00p, e01 = *e01p, e10 = *e10p, e11 = *e11p;
  float a00x = 0.f, a00y = 0.f, a01x = 0.f, a01y = 0.f;
  float a10x = 0.f, a10y = 0.f, a11x = 0.f, a11y = 0.f;
  #pragma unroll 4
  for (int g = 0; g < F; g += 4) {
    float4 L0 = *reinterpret_cast<const float4*>(&hls[ti][g]);
    float4 L1 = *reinterpret_cast<const float4*>(&hls[ti + 16][g]);
    float4 R0 = *reinterpret_cast<const float4*>(&hrs[tj][g]);
    float4 R1 = *reinterpret_cast<const float4*>(&hrs[tj + 16][g]);
    float4 W0 = *reinterpret_cast<const float4*>(&wps[0][g]);  // uniform -> broadcast
    float4 W1 = *reinterpret_cast<const float4*>(&wps[1][g]);
    float4 P0 = *reinterpret_cast<const float4*>(&wps[2][g]);
    float4 P1 = *reinterpret_cast<const float4*>(&wps[3][g]);
#define DO_COMP(K)                                                             \
    {                                                                          \
      float w0 = W0.K, w1v = W1.K, p0 = P0.K, p1 = P1.K;                       \
      float v;                                                                 \
      v = L0.K + R0.K; v = fmaf(e00.x, w0, v); v = fmaf(e00.y, w1v, v);        \
      v = fmaxf(v, NSLOPE * v);                                                \
      a00x = fmaf(p0, v, a00x); a00y = fmaf(p1, v, a00y);                      \
      v = L0.K + R1.K; v = fmaf(e01.x, w0, v); v = fmaf(e01.y, w1v, v);        \
      v = fmaxf(v, NSLOPE * v);                                                \
      a01x = fmaf(p0, v, a01x); a01y = fmaf(p1, v, a01y);                      \
      v = L1.K + R0.K; v = fmaf(e10.x, w0, v); v = fmaf(e10.y, w1v, v);        \
      v = fmaxf(v, NSLOPE * v);                                                \
      a10x = fmaf(p0, v, a10x); a10y = fmaf(p1, v, a10y);                      \
      v = L1.K + R1.K; v = fmaf(e11.x, w0, v); v = fmaf(e11.y, w1v, v);        \
      v = fmaxf(v, NSLOPE * v);                                                \
      a11x = fmaf(p0, v, a11x); a11y = fmaf(p1, v, a11y);                      \
    }
    DO_COMP(x) DO_COMP(y) DO_COMP(z) DO_COMP(w)
#undef DO_COMP
  }
  float c0 = ws[WS_C + 0], c1 = ws[WS_C + 1];
  float2 o;
  o.x = a00x + c0; o.y = a00y + c1;
  *reinterpret_cast<float2*>(out + ((size_t)(b * N + i1) * N + j1) * 2) = o;
  o.x = a01x + c0; o.y = a01y + c1;
  *reinterpret_cast<float2*>(out + ((size_t)(b * N + i1) * N + j2) * 2) = o;
  o.x = a10x + c0; o.y = a10y + c1;
  *reinterpret_cast<float2*>(out + ((size_t)(b * N + i2) * N + j1) * 2) = o;
  o.x = a11x + c0; o.y = a11y + c1;
  *reinterpret_cast<float2*>(out + ((size_t)(b * N + i2) * N + j2) * 2) = o;
}

extern "C" void kernel_launch(void* const* d_in, const int* in_sizes, int n_in,
                              void* d_out, int out_size, void* d_ws, size_t ws_size,
                              hipStream_t stream) {
  const float* node = (const float*)d_in[0];
  const float* edge = (const float*)d_in[1];
  const float* w1   = (const float*)d_in[2];
  const float* g1   = (const float*)d_in[3];
  const float* b1   = (const float*)d_in[4];
  const float* m1   = (const float*)d_in[5];
  const float* v1   = (const float*)d_in[6];
  const float* w2   = (const float*)d_in[7];
  const float* g2   = (const float*)d_in[8];
  const float* b2   = (const float*)d_in[9];
  const float* m2   = (const float*)d_in[10];
  const float* v2   = (const float*)d_in[11];
  const float* pw   = (const float*)d_in[12];
  const float* pb   = (const float*)d_in[13];
  float* ws  = (float*)d_ws;
  float* out = (float*)d_out;

  prepA<<<1 + F, 128, 0, stream>>>(w1, g1, b1, m1, v1, w2, g2, b2, m2, v2, pw, pb, ws);
  prepB<<<256, 128, 0, stream>>>(node, ws, ws);
  fused_main<<<dim3(N / 32, N / 32, B), 256, 0, stream>>>(edge, ws, out);
}

// Round 3
// 29.948 us; speedup vs baseline: 1.1227x; 1.1227x over previous
//
#include <hip/hip_runtime.h>

#define EPS    1e-5f
#define NSLOPE 0.01f
#define B 4
#define N 256
#define F 128

// workspace float layout
#define WS_WE0 0                 // we0[g]*s1[g]            (128)
#define WS_WE1 128               // we1[g]*s1[g]            (128)
#define WS_PF0 256               // weff[0][g]              (128)
#define WS_PF1 384               // weff[1][g]              (128)
#define WS_C   512               // c[0..1]
#define WS_HL  1024              // hl''[row,g] = hl*s1+t1  (B*N*F)
#define WS_HR  (WS_HL + B*N*F)   // hr'[row,g]  = hr*s1     (B*N*F)

// ---------------------------------------------------------------- prep_all
// grid 257 blocks x 128 threads.
// blocks 0..255: hl/hr. 16 row-chunks (64 rows) x 16 g-chunks (8 g).
//   Wave (64 lanes) = 64 rows; wave w handles g0..g0+3. Weight reads are
//   wave-uniform -> s_load (scalar pipe); node reads per-lane from L1/L2.
// block 256: fold affine head/tail into WE/PF/C.
__global__ __launch_bounds__(128) void prep_all(
    const float* __restrict__ node, const float* __restrict__ w1,
    const float* __restrict__ g1, const float* __restrict__ b1,
    const float* __restrict__ m1, const float* __restrict__ v1,
    const float* __restrict__ w2, const float* __restrict__ g2,
    const float* __restrict__ b2, const float* __restrict__ m2,
    const float* __restrict__ v2, const float* __restrict__ pw,
    const float* __restrict__ pb, float* __restrict__ ws) {
  if (blockIdx.x == 256) {
    __shared__ float s2s[F], t2s[F];
    int g = threadIdx.x;
    float s1v = g1[g] / sqrtf(v1[g] + EPS);
    ws[WS_WE0 + g] = w1[g * 258 + 0] * s1v;
    ws[WS_WE1 + g] = w1[g * 258 + 1] * s1v;
    float s2v = g2[g] / sqrtf(v2[g] + EPS);
    s2s[g] = s2v;
    t2s[g] = b2[g] - m2[g] * s2v;
    __syncthreads();
    float a0 = 0.f, a1 = 0.f;
    for (int f = 0; f < F; ++f) {
      float wv = w2[f * F + g];               // coalesced (g fastest)
      a0 = fmaf(pw[f]     * s2s[f], wv, a0);
      a1 = fmaf(pw[F + f] * s2s[f], wv, a1);
    }
    ws[WS_PF0 + g] = a0;
    ws[WS_PF1 + g] = a1;
    if (g < 2) {
      float c = pb[g];
      for (int f = 0; f < F; ++f) c += pw[g * F + f] * t2s[f];
      ws[WS_C + g] = c;
    }
    return;
  }
  int rc = blockIdx.x >> 4;                    // 16 row chunks of 64
  int gc = blockIdx.x & 15;                    // 16 g chunks of 8
  int lane = threadIdx.x & 63;
  int wv = __builtin_amdgcn_readfirstlane(threadIdx.x >> 6);  // 0..1, SGPR
  int row = rc * 64 + lane;
  int g0 = gc * 8 + wv * 4;
  const float4* nrow = reinterpret_cast<const float4*>(node + (size_t)row * F);
  float accl[4] = {0.f, 0.f, 0.f, 0.f};
  float accr[4] = {0.f, 0.f, 0.f, 0.f};
  #pragma unroll 8
  for (int q = 0; q < 32; ++q) {
    float4 nv = nrow[q];
    #pragma unroll
    for (int k = 0; k < 4; ++k) {
      const float* wrow = w1 + (size_t)(g0 + k) * 258;   // wave-uniform -> s_load
      float2 wl0 = *reinterpret_cast<const float2*>(wrow + 2 + 4 * q);
      float2 wl1 = *reinterpret_cast<const float2*>(wrow + 4 + 4 * q);
      float2 wr0 = *reinterpret_cast<const float2*>(wrow + 130 + 4 * q);
      float2 wr1 = *reinterpret_cast<const float2*>(wrow + 132 + 4 * q);
      accl[k] = fmaf(nv.x, wl0.x, accl[k]);
      accl[k] = fmaf(nv.y, wl0.y, accl[k]);
      accl[k] = fmaf(nv.z, wl1.x, accl[k]);
      accl[k] = fmaf(nv.w, wl1.y, accl[k]);
      accr[k] = fmaf(nv.x, wr0.x, accr[k]);
      accr[k] = fmaf(nv.y, wr0.y, accr[k]);
      accr[k] = fmaf(nv.z, wr1.x, accr[k]);
      accr[k] = fmaf(nv.w, wr1.y, accr[k]);
    }
  }
  float* hl = ws + WS_HL;
  float* hr = ws + WS_HR;
  #pragma unroll
  for (int k = 0; k < 4; ++k) {
    int g = g0 + k;
    float s1v = g1[g] / sqrtf(v1[g] + EPS);    // uniform, tiny
    float t1v = b1[g] - m1[g] * s1v;
    hl[(size_t)row * F + g] = fmaf(accl[k], s1v, t1v);
    hr[(size_t)row * F + g] = accr[k] * s1v;
  }
}

// ---------------------------------------------------------------- main
// grid (8,8,B), block 256: 32x32 (i,j) tile, 2x2 outputs per thread.
// hl/hr tiles staged in LDS; WE/PF/C read as wave-uniform globals (s_load).
__global__ __launch_bounds__(256) void fused_main(
    const float* __restrict__ edge,
    const float* __restrict__ ws, float* __restrict__ out) {
  __shared__ float hls[32][132];
  __shared__ float hrs[32][132];
  int b = blockIdx.z, i0 = blockIdx.y * 32, j0 = blockIdx.x * 32;
  int t = threadIdx.x;
  int ti = t >> 4, tj = t & 15;
  int i1 = i0 + ti, i2 = i1 + 16, j1 = j0 + tj, j2 = j1 + 16;
  // issue edge loads early (independent of LDS staging)
  float2 e00 = *reinterpret_cast<const float2*>(edge + ((size_t)(b * N + i1) * N + j1) * 2);
  float2 e01 = *reinterpret_cast<const float2*>(edge + ((size_t)(b * N + i1) * N + j2) * 2);
  float2 e10 = *reinterpret_cast<const float2*>(edge + ((size_t)(b * N + i2) * N + j1) * 2);
  float2 e11 = *reinterpret_cast<const float2*>(edge + ((size_t)(b * N + i2) * N + j2) * 2);
  {
    const float* hl = ws + WS_HL;
    const float* hr = ws + WS_HR;
    int r = t >> 3, cq = (t & 7) * 16;
    const float* sl = hl + (size_t)(b * N + i0 + r) * F + cq;
    const float* sr = hr + (size_t)(b * N + j0 + r) * F + cq;
    #pragma unroll
    for (int k = 0; k < 4; ++k) {
      *reinterpret_cast<float4*>(&hls[r][cq + 4 * k]) =
          *reinterpret_cast<const float4*>(sl + 4 * k);
      *reinterpret_cast<float4*>(&hrs[r][cq + 4 * k]) =
          *reinterpret_cast<const float4*>(sr + 4 * k);
    }
  }
  __syncthreads();
  const float4* W0p = reinterpret_cast<const float4*>(ws + WS_WE0);  // uniform -> s_load
  const float4* W1p = reinterpret_cast<const float4*>(ws + WS_WE1);
  const float4* P0p = reinterpret_cast<const float4*>(ws + WS_PF0);
  const float4* P1p = reinterpret_cast<const float4*>(ws + WS_PF1);
  float a00x = 0.f, a00y = 0.f, a01x = 0.f, a01y = 0.f;
  float a10x = 0.f, a10y = 0.f, a11x = 0.f, a11y = 0.f;
  #pragma unroll 4
  for (int gq = 0; gq < F / 4; ++gq) {
    int g = gq * 4;
    float4 L0 = *reinterpret_cast<const float4*>(&hls[ti][g]);
    float4 L1 = *reinterpret_cast<const float4*>(&hls[ti + 16][g]);
    float4 R0 = *reinterpret_cast<const float4*>(&hrs[tj][g]);
    float4 R1 = *reinterpret_cast<const float4*>(&hrs[tj + 16][g]);
    float4 W0 = W0p[gq];
    float4 W1 = W1p[gq];
    float4 P0 = P0p[gq];
    float4 P1 = P1p[gq];
#define DO_COMP(K)                                                             \
    {                                                                          \
      float w0 = W0.K, w1v = W1.K, p0 = P0.K, p1 = P1.K;                       \
      float v;                                                                 \
      v = L0.K + R0.K; v = fmaf(e00.x, w0, v); v = fmaf(e00.y, w1v, v);        \
      v = fmaxf(v, NSLOPE * v);                                                \
      a00x = fmaf(p0, v, a00x); a00y = fmaf(p1, v, a00y);                      \
      v = L0.K + R1.K; v = fmaf(e01.x, w0, v); v = fmaf(e01.y, w1v, v);        \
      v = fmaxf(v, NSLOPE * v);                                                \
      a01x = fmaf(p0, v, a01x); a01y = fmaf(p1, v, a01y);                      \
      v = L1.K + R0.K; v = fmaf(e10.x, w0, v); v = fmaf(e10.y, w1v, v);        \
      v = fmaxf(v, NSLOPE * v);                                                \
      a10x = fmaf(p0, v, a10x); a10y = fmaf(p1, v, a10y);                      \
      v = L1.K + R1.K; v = fmaf(e11.x, w0, v); v = fmaf(e11.y, w1v, v);        \
      v = fmaxf(v, NSLOPE * v);                                                \
      a11x = fmaf(p0, v, a11x); a11y = fmaf(p1, v, a11y);                      \
    }
    DO_COMP(x) DO_COMP(y) DO_COMP(z) DO_COMP(w)
#undef DO_COMP
  }
  float c0 = ws[WS_C + 0], c1 = ws[WS_C + 1];
  float2 o;
  o.x = a00x + c0; o.y = a00y + c1;
  *reinterpret_cast<float2*>(out + ((size_t)(b * N + i1) * N + j1) * 2) = o;
  o.x = a01x + c0; o.y = a01y + c1;
  *reinterpret_cast<float2*>(out + ((size_t)(b * N + i1) * N + j2) * 2) = o;
  o.x = a10x + c0; o.y = a10y + c1;
  *reinterpret_cast<float2*>(out + ((size_t)(b * N + i2) * N + j1) * 2) = o;
  o.x = a11x + c0; o.y = a11y + c1;
  *reinterpret_cast<float2*>(out + ((size_t)(b * N + i2) * N + j2) * 2) = o;
}

extern "C" void kernel_launch(void* const* d_in, const int* in_sizes, int n_in,
                              void* d_out, int out_size, void* d_ws, size_t ws_size,
                              hipStream_t stream) {
  const float* node = (const float*)d_in[0];
  const float* edge = (const float*)d_in[1];
  const float* w1   = (const float*)d_in[2];
  const float* g1   = (const float*)d_in[3];
  const float* b1   = (const float*)d_in[4];
  const float* m1   = (const float*)d_in[5];
  const float* v1   = (const float*)d_in[6];
  const float* w2   = (const float*)d_in[7];
  const float* g2   = (const float*)d_in[8];
  const float* b2   = (const float*)d_in[9];
  const float* m2   = (const float*)d_in[10];
  const float* v2   = (const float*)d_in[11];
  const float* pw   = (const float*)d_in[12];
  const float* pb   = (const float*)d_in[13];
  float* ws  = (float*)d_ws;
  float* out = (float*)d_out;

  prep_all<<<257, 128, 0, stream>>>(node, w1, g1, b1, m1, v1, w2, g2, b2, m2,
                                    v2, pw, pb, ws);
  fused_main<<<dim3(N / 32, N / 32, B), 256, 0, stream>>>(edge, ws, out);
}